// Round 1
// baseline (241.964 us; speedup 1.0000x reference)
//
#include <hip/hip_runtime.h>

// Problem constants
#define TT    2048     // time steps
#define NB    32       // batch
#define NF    64       // features incl. time channel (63 + 1)
#define NL    10       // levels
#define NU    64       // units
#define TTILE 64       // t per block (kernel 1)
#define UQ    16       // u per block (kernel 1)
#define SUBT  16       // t per scan sub-chunk
#define NSUB  4        // sub-chunks per block
#define NCHUNK 128     // total chunks = TT/SUBT
#define NW    20       // iterated-sum words per (b,chunk,u)

// LDS layout (floats)
#define DX_STRIDE  68              // 64 + 4 pad (16B-aligned rows, 2-way max bank alias)
#define DX_WORDS   (TTILE * DX_STRIDE)          // 4352
#define KT_USTRIDE 644             // 10*64 + 4 pad (16B-aligned, 2-way max bank alias)
#define KT_WORDS   (UQ * KT_USTRIDE)            // 10304
#define DT_TSTRIDE 160             // d-tile: [t][l*16+ul]

// Kernel 1: per (b, t-tile, u-quarter): GEMM d = dX * K  ->  chunk iterated sums L
__global__ __launch_bounds__(256, 2)
void k_gemm_scan(const float* __restrict__ x, const float* __restrict__ K,
                 float* __restrict__ L) {
    __shared__ float sm[DX_WORDS + KT_WORDS];   // 58,624 B
    float* dx = sm;                // [64][68]
    float* kt = sm + DX_WORDS;     // [16][644]  (l*64 + f within row)
    float* dtile = kt;             // aliased after GEMM: [t][l*16 + ul]

    const int tid   = threadIdx.x;
    const int ttile = blockIdx.x;  // 0..31
    const int uq    = blockIdx.y;  // 0..3
    const int b     = blockIdx.z;  // 0..31
    const int t0    = ttile * TTILE;
    const int uh    = uq * UQ;
    const float dtc = 2.0f / (float)(TT - 1);

    // ---- stage dX (time-diffed input, incl. time channel) ----
    for (int idx = tid; idx < TTILE * 64; idx += 256) {
        const int t = idx >> 6, f = idx & 63;
        const int tg = t0 + t;
        float v;
        if (tg == 0)        v = 0.0f;
        else if (f == 63)   v = dtc;
        else                v = x[(size_t)(b * TT + tg) * 63 + f]
                              - x[(size_t)(b * TT + tg - 1) * 63 + f];
        dx[t * DX_STRIDE + f] = v;
    }
    // ---- stage K transposed: kt[ul][l][f] = K[f][l][uh+ul] ----
    for (int idx = tid; idx < UQ * NL * 64; idx += 256) {
        const int ul = idx & 15;
        const int l  = (idx >> 4) % 10;
        const int f  = idx / 160;
        kt[ul * KT_USTRIDE + l * 64 + f] = K[(size_t)(f * NL + l) * NU + uh + ul];
    }
    __syncthreads();

    // ---- GEMM: thread computes d[t0+tg*4 .. +3][0..9][uh+ul] ----
    const int tg = tid >> 4;   // 0..15
    const int ul = tid & 15;   // 0..15
    float acc[4][10];
#pragma unroll
    for (int i = 0; i < 4; ++i)
#pragma unroll
        for (int l = 0; l < 10; ++l) acc[i][l] = 0.0f;

    const float* dxp = dx + tg * 4 * DX_STRIDE;
    const float* ktp = kt + ul * KT_USTRIDE;
#pragma unroll 4
    for (int f = 0; f < 64; f += 4) {
        float4 xv[4];
#pragma unroll
        for (int i = 0; i < 4; ++i)
            xv[i] = *reinterpret_cast<const float4*>(dxp + i * DX_STRIDE + f);
#pragma unroll
        for (int l = 0; l < 10; ++l) {
            const float4 kv = *reinterpret_cast<const float4*>(ktp + l * 64 + f);
#pragma unroll
            for (int i = 0; i < 4; ++i) {
                acc[i][l] += xv[i].x * kv.x;
                acc[i][l] += xv[i].y * kv.y;
                acc[i][l] += xv[i].z * kv.z;
                acc[i][l] += xv[i].w * kv.w;
            }
        }
    }
    __syncthreads();   // done reading kt; safe to alias as dtile

    // ---- scatter d into LDS d-tile [t][l*16+ul] ----
#pragma unroll
    for (int i = 0; i < 4; ++i)
#pragma unroll
        for (int l = 0; l < 10; ++l)
            dtile[(tg * 4 + i) * DT_TSTRIDE + l * 16 + ul] = acc[i][l];
    __syncthreads();

    // ---- chunk scan: wave = one 16-step sub-chunk; lanes = 4 chains x 16 u ----
    const int sub   = tid >> 6;        // 0..3 (wave id)
    const int chain = (tid >> 4) & 3;  // 0..3
    const int su    = tid & 15;        // u within quarter
    float S[10];
#pragma unroll
    for (int i = 0; i < 10; ++i) S[i] = 0.0f;

    const int tstart = sub * SUBT;
    const float* dp = dtile + su;

    if (chain == 0) {
        for (int t = tstart; t < tstart + SUBT; ++t)
            S[0] += dp[t * DT_TSTRIDE + 0 * 16];
    } else if (chain == 1) {
        // S0=s1 S1=s2 S2=s12
        for (int t = tstart; t < tstart + SUBT; ++t) {
            const float d1 = dp[t * DT_TSTRIDE + 1 * 16];
            const float d2 = dp[t * DT_TSTRIDE + 2 * 16];
            S[2] += S[0] * d2;
            S[0] += d1;  S[1] += d2;
        }
    } else if (chain == 2) {
        // S0=s3 S1=s4 S2=s5 S3=s34 S4=s45 S5=s345
        for (int t = tstart; t < tstart + SUBT; ++t) {
            const float d3 = dp[t * DT_TSTRIDE + 3 * 16];
            const float d4 = dp[t * DT_TSTRIDE + 4 * 16];
            const float d5 = dp[t * DT_TSTRIDE + 5 * 16];
            S[5] += S[3] * d5;                 // s345 += s34*d5
            S[3] += S[0] * d4;                 // s34  += s3*d4
            S[4] += S[1] * d5;                 // s45  += s4*d5
            S[0] += d3;  S[1] += d4;  S[2] += d5;
        }
    } else {
        // S0=s6 S1=s7 S2=s8 S3=s9 S4=s67 S5=s78 S6=s89 S7=s678 S8=s789 S9=s6789
        for (int t = tstart; t < tstart + SUBT; ++t) {
            const float d6 = dp[t * DT_TSTRIDE + 6 * 16];
            const float d7 = dp[t * DT_TSTRIDE + 7 * 16];
            const float d8 = dp[t * DT_TSTRIDE + 8 * 16];
            const float d9 = dp[t * DT_TSTRIDE + 9 * 16];
            S[9] += S[7] * d9;                 // s6789 += s678*d9
            S[7] += S[4] * d8;                 // s678  += s67*d8
            S[8] += S[5] * d9;                 // s789  += s78*d9
            S[4] += S[0] * d7;                 // s67   += s6*d7
            S[5] += S[1] * d8;                 // s78   += s7*d8
            S[6] += S[2] * d9;                 // s89   += s8*d9
            S[0] += d6;  S[1] += d7;  S[2] += d8;  S[3] += d9;
        }
    }

    // ---- write the 20 words for (b, chunk, u) ----
    const int c = ttile * NSUB + sub;  // global chunk 0..127
    float* Lb = L + ((size_t)(b * NCHUNK + c) * NW) * NU + (uh + su);
    if (chain == 0) {
        Lb[0 * NU] = S[0];
    } else if (chain == 1) {
        Lb[1 * NU] = S[0];  Lb[2 * NU] = S[1];  Lb[3 * NU] = S[2];
    } else if (chain == 2) {
        Lb[4 * NU] = S[0];  Lb[5 * NU] = S[1];  Lb[6 * NU] = S[2];
        Lb[7 * NU] = S[3];  Lb[8 * NU] = S[4];  Lb[9 * NU] = S[5];
    } else {
        Lb[10 * NU] = S[0]; Lb[11 * NU] = S[1]; Lb[12 * NU] = S[2]; Lb[13 * NU] = S[3];
        Lb[14 * NU] = S[4]; Lb[15 * NU] = S[5]; Lb[16 * NU] = S[6];
        Lb[17 * NU] = S[7]; Lb[18 * NU] = S[8]; Lb[19 * NU] = S[9];
    }
}

// Kernel 2: fold chunk sums across c via Chen's relation; one thread per (b,u)
__global__ __launch_bounds__(256)
void k_fold(const float* __restrict__ L, float* __restrict__ out) {
    const int gid = blockIdx.x * 256 + threadIdx.x;   // 0..2047
    const int b = gid >> 6, u = gid & 63;
    float G0 = 0.f, G1 = 0.f, G12 = 0.f, G3 = 0.f, G34 = 0.f, G345 = 0.f;
    float G6 = 0.f, G67 = 0.f, G678 = 0.f, G6789 = 0.f;
    for (int c = 0; c < NCHUNK; ++c) {
        const float* Lb = L + ((size_t)(b * NCHUNK + c) * NW) * NU + u;
        float Lw[NW];
#pragma unroll
        for (int w = 0; w < NW; ++w) Lw[w] = Lb[w * NU];
        // longest-first so shorter G prefixes are still "old"
        G6789 += G678 * Lw[13] + G67 * Lw[16] + G6 * Lw[18] + Lw[19];
        G678  += G67 * Lw[12] + G6 * Lw[15] + Lw[17];
        G67   += G6 * Lw[11] + Lw[14];
        G6    += Lw[10];
        G345  += G34 * Lw[6] + G3 * Lw[8] + Lw[9];
        G34   += G3 * Lw[5] + Lw[7];
        G3    += Lw[4];
        G12   += G1 * Lw[2] + Lw[3];
        G1    += Lw[1];
        G0    += Lw[0];
    }
    out[gid] = G0 + G12 + G345 + G6789;
}

extern "C" void kernel_launch(void* const* d_in, const int* in_sizes, int n_in,
                              void* d_out, int out_size, void* d_ws, size_t ws_size,
                              hipStream_t stream) {
    const float* x = (const float*)d_in[0];   // (32, 2048, 63) fp32
    const float* K = (const float*)d_in[1];   // (64, 10, 64)  fp32
    float* out = (float*)d_out;               // (32, 64) fp32
    float* L   = (float*)d_ws;                // needs 32*128*20*64*4 = 20,971,520 B

    dim3 g1(TT / TTILE, NU / UQ, NB);         // (32, 4, 32)
    k_gemm_scan<<<g1, 256, 0, stream>>>(x, K, L);
    k_fold<<<(NB * NU) / 256, 256, 0, stream>>>(L, out);
}

// Round 2
// 209.955 us; speedup vs baseline: 1.1525x; 1.1525x over previous
//
#include <hip/hip_runtime.h>

// Problem constants
#define TT    2048     // time steps
#define NB    32       // batch
#define NF    64       // features incl. time channel (63 + 1)
#define NL    10       // levels
#define NU    64       // units
#define TTILE 64       // t per block (kernel 1)
#define UQ    16       // u per block (kernel 1)
#define SUBT  16       // t per scan sub-chunk
#define NSUB  4        // sub-chunks per block
#define NCHUNK 128     // total chunks = TT/SUBT
#define NW    20       // iterated-sum words per (b,chunk,u)

// LDS layout (floats)
#define DX_STRIDE  68              // 64 + 4 pad
#define DX_WORDS   (TTILE * DX_STRIDE)          // 4352
#define KT_USTRIDE 644             // 10*64 + 4 pad
#define KT_WORDS   (UQ * KT_USTRIDE)            // 10304
#define DT_TSTRIDE 161             // d-tile stride: 64*161 = 10304 fits kt region exactly;
                                   // 161 mod 32 = 1 breaks the 4-way scatter conflict

// Chen composition C = A ∘ B over the 20-word alphabet:
// 0:(0) | 1:(1) 2:(2) 3:(12) | 4:(3) 5:(4) 6:(5) 7:(34) 8:(45) 9:(345)
// 10:(6) 11:(7) 12:(8) 13:(9) 14:(67) 15:(78) 16:(89) 17:(678) 18:(789) 19:(6789)
__device__ inline void chen_combine(const float* A, const float* B, float* C) {
    C[0]  = A[0] + B[0];
    C[1]  = A[1] + B[1];
    C[2]  = A[2] + B[2];
    C[3]  = A[3] + A[1]*B[2] + B[3];
    C[4]  = A[4] + B[4];
    C[5]  = A[5] + B[5];
    C[6]  = A[6] + B[6];
    C[7]  = A[7] + A[4]*B[5] + B[7];
    C[8]  = A[8] + A[5]*B[6] + B[8];
    C[9]  = A[9] + A[7]*B[6] + A[4]*B[8] + B[9];
    C[10] = A[10] + B[10];
    C[11] = A[11] + B[11];
    C[12] = A[12] + B[12];
    C[13] = A[13] + B[13];
    C[14] = A[14] + A[10]*B[11] + B[14];
    C[15] = A[15] + A[11]*B[12] + B[15];
    C[16] = A[16] + A[12]*B[13] + B[16];
    C[17] = A[17] + A[14]*B[12] + A[10]*B[15] + B[17];
    C[18] = A[18] + A[15]*B[13] + A[11]*B[16] + B[18];
    C[19] = A[19] + A[17]*B[13] + A[14]*B[16] + A[10]*B[18] + B[19];
}

// Kernel 1: per (b, t-tile, u-quarter): GEMM d = dX * K  ->  chunk iterated sums L
__global__ __launch_bounds__(256, 2)
void k_gemm_scan(const float* __restrict__ x, const float* __restrict__ K,
                 float* __restrict__ L) {
    __shared__ float sm[DX_WORDS + KT_WORDS];   // 58,624 B
    float* dx = sm;                // [64][68]
    float* kt = sm + DX_WORDS;     // [16][644]  (l*64 + f within row)
    float* dtile = kt;             // aliased after GEMM: [t*161 + l*16 + ul]

    const int tid   = threadIdx.x;
    const int ttile = blockIdx.x;  // 0..31
    const int uq    = blockIdx.y;  // 0..3
    const int b     = blockIdx.z;  // 0..31
    const int t0    = ttile * TTILE;
    const int uh    = uq * UQ;
    const float dtc = 2.0f / (float)(TT - 1);

    // ---- stage dX (time-diffed input, incl. time channel) ----
    for (int idx = tid; idx < TTILE * 64; idx += 256) {
        const int t = idx >> 6, f = idx & 63;
        const int tg = t0 + t;
        float v;
        if (tg == 0)        v = 0.0f;
        else if (f == 63)   v = dtc;
        else                v = x[(size_t)(b * TT + tg) * 63 + f]
                              - x[(size_t)(b * TT + tg - 1) * 63 + f];
        dx[t * DX_STRIDE + f] = v;
    }
    // ---- stage K transposed: kt[ul][l][f] = K[f][l][uh+ul] ----
    for (int idx = tid; idx < UQ * NL * 64; idx += 256) {
        const int ul = idx & 15;
        const int l  = (idx >> 4) % 10;
        const int f  = idx / 160;
        kt[ul * KT_USTRIDE + l * 64 + f] = K[(size_t)(f * NL + l) * NU + uh + ul];
    }
    __syncthreads();

    // ---- GEMM: thread computes d[t0+tg*4 .. +3][0..9][uh+ul] ----
    const int tg = tid >> 4;   // 0..15
    const int ul = tid & 15;   // 0..15
    float acc[4][10];
#pragma unroll
    for (int i = 0; i < 4; ++i)
#pragma unroll
        for (int l = 0; l < 10; ++l) acc[i][l] = 0.0f;

    const float* dxp = dx + tg * 4 * DX_STRIDE;
    const float* ktp = kt + ul * KT_USTRIDE;
#pragma unroll 4
    for (int f = 0; f < 64; f += 4) {
        float4 xv[4];
#pragma unroll
        for (int i = 0; i < 4; ++i)
            xv[i] = *reinterpret_cast<const float4*>(dxp + i * DX_STRIDE + f);
#pragma unroll
        for (int l = 0; l < 10; ++l) {
            const float4 kv = *reinterpret_cast<const float4*>(ktp + l * 64 + f);
#pragma unroll
            for (int i = 0; i < 4; ++i) {
                acc[i][l] += xv[i].x * kv.x;
                acc[i][l] += xv[i].y * kv.y;
                acc[i][l] += xv[i].z * kv.z;
                acc[i][l] += xv[i].w * kv.w;
            }
        }
    }
    __syncthreads();   // done reading kt; safe to alias as dtile

    // ---- scatter d into LDS d-tile [t*161 + l*16 + ul] ----
#pragma unroll
    for (int i = 0; i < 4; ++i)
#pragma unroll
        for (int l = 0; l < 10; ++l)
            dtile[(tg * 4 + i) * DT_TSTRIDE + l * 16 + ul] = acc[i][l];
    __syncthreads();

    // ---- chunk scan: WAVE = chain (wave-uniform branch, no divergence);
    //      lanes = 4 sub-chunks x 16 u ----
    const int wv  = tid >> 6;        // 0..3 = chain
    const int sub = (tid >> 4) & 3;  // sub-chunk
    const int su  = tid & 15;        // u within quarter
    float S[10];
#pragma unroll
    for (int i = 0; i < 10; ++i) S[i] = 0.0f;

    const int tstart = sub * SUBT;
    const float* dp = dtile + su;

    if (wv == 0) {
        for (int t = tstart; t < tstart + SUBT; ++t)
            S[0] += dp[t * DT_TSTRIDE + 0 * 16];
    } else if (wv == 1) {
        // S0=s1 S1=s2 S2=s12
        for (int t = tstart; t < tstart + SUBT; ++t) {
            const float d1 = dp[t * DT_TSTRIDE + 1 * 16];
            const float d2 = dp[t * DT_TSTRIDE + 2 * 16];
            S[2] += S[0] * d2;
            S[0] += d1;  S[1] += d2;
        }
    } else if (wv == 2) {
        // S0=s3 S1=s4 S2=s5 S3=s34 S4=s45 S5=s345
        for (int t = tstart; t < tstart + SUBT; ++t) {
            const float d3 = dp[t * DT_TSTRIDE + 3 * 16];
            const float d4 = dp[t * DT_TSTRIDE + 4 * 16];
            const float d5 = dp[t * DT_TSTRIDE + 5 * 16];
            S[5] += S[3] * d5;
            S[3] += S[0] * d4;
            S[4] += S[1] * d5;
            S[0] += d3;  S[1] += d4;  S[2] += d5;
        }
    } else {
        // S0=s6 S1=s7 S2=s8 S3=s9 S4=s67 S5=s78 S6=s89 S7=s678 S8=s789 S9=s6789
        for (int t = tstart; t < tstart + SUBT; ++t) {
            const float d6 = dp[t * DT_TSTRIDE + 6 * 16];
            const float d7 = dp[t * DT_TSTRIDE + 7 * 16];
            const float d8 = dp[t * DT_TSTRIDE + 8 * 16];
            const float d9 = dp[t * DT_TSTRIDE + 9 * 16];
            S[9] += S[7] * d9;
            S[7] += S[4] * d8;
            S[8] += S[5] * d9;
            S[4] += S[0] * d7;
            S[5] += S[1] * d8;
            S[6] += S[2] * d9;
            S[0] += d6;  S[1] += d7;  S[2] += d8;  S[3] += d9;
        }
    }

    // ---- write the 20 words for (b, chunk, u) ----
    const int c = ttile * NSUB + sub;  // global chunk 0..127
    float* Lb = L + ((size_t)(b * NCHUNK + c) * NW) * NU + (uh + su);
    if (wv == 0) {
        Lb[0 * NU] = S[0];
    } else if (wv == 1) {
        Lb[1 * NU] = S[0];  Lb[2 * NU] = S[1];  Lb[3 * NU] = S[2];
    } else if (wv == 2) {
        Lb[4 * NU] = S[0];  Lb[5 * NU] = S[1];  Lb[6 * NU] = S[2];
        Lb[7 * NU] = S[3];  Lb[8 * NU] = S[4];  Lb[9 * NU] = S[5];
    } else {
        Lb[10 * NU] = S[0]; Lb[11 * NU] = S[1]; Lb[12 * NU] = S[2]; Lb[13 * NU] = S[3];
        Lb[14 * NU] = S[4]; Lb[15 * NU] = S[5]; Lb[16 * NU] = S[6];
        Lb[17 * NU] = S[7]; Lb[18 * NU] = S[8]; Lb[19 * NU] = S[9];
    }
}

// Kernel 2: fold chunks via Chen's relation. One block per b;
// 4 waves each fold a 32-chunk quarter (u = lane, coalesced), then
// cross-wave combine through LDS.
__global__ __launch_bounds__(256)
void k_fold(const float* __restrict__ L, float* __restrict__ out) {
    __shared__ float smE[3][NW][NU];    // 15,360 B
    const int b = blockIdx.x;
    const int u = threadIdx.x & 63;
    const int q = threadIdx.x >> 6;     // wave = quarter of the chunk axis
    const float* Lb = L + (size_t)b * NCHUNK * NW * NU + u;

    float E[NW];
    const int c0 = q * (NCHUNK / 4);
    {
        const float* p = Lb + (size_t)c0 * NW * NU;
#pragma unroll
        for (int w = 0; w < NW; ++w) E[w] = p[w * NU];
    }
    for (int c = c0 + 1; c < c0 + NCHUNK / 4; ++c) {
        const float* pc = Lb + (size_t)c * NW * NU;
        float Bw[NW], Cw[NW];
#pragma unroll
        for (int w = 0; w < NW; ++w) Bw[w] = pc[w * NU];
        chen_combine(E, Bw, Cw);
#pragma unroll
        for (int w = 0; w < NW; ++w) E[w] = Cw[w];
    }

    if (q > 0) {
#pragma unroll
        for (int w = 0; w < NW; ++w) smE[q - 1][w][u] = E[w];
    }
    __syncthreads();
    if (q == 0) {
        for (int j = 0; j < 3; ++j) {
            float Bw[NW], Cw[NW];
#pragma unroll
            for (int w = 0; w < NW; ++w) Bw[w] = smE[j][w][u];
            chen_combine(E, Bw, Cw);
#pragma unroll
            for (int w = 0; w < NW; ++w) E[w] = Cw[w];
        }
        out[b * NU + u] = E[0] + E[3] + E[9] + E[19];
    }
}

extern "C" void kernel_launch(void* const* d_in, const int* in_sizes, int n_in,
                              void* d_out, int out_size, void* d_ws, size_t ws_size,
                              hipStream_t stream) {
    const float* x = (const float*)d_in[0];   // (32, 2048, 63) fp32
    const float* K = (const float*)d_in[1];   // (64, 10, 64)  fp32
    float* out = (float*)d_out;               // (32, 64) fp32
    float* L   = (float*)d_ws;                // 32*128*20*64*4 = 20,971,520 B

    dim3 g1(TT / TTILE, NU / UQ, NB);         // (32, 4, 32)
    k_gemm_scan<<<g1, 256, 0, stream>>>(x, K, L);
    k_fold<<<NB, 256, 0, stream>>>(L, out);
}

// Round 3
// 136.765 us; speedup vs baseline: 1.7692x; 1.5352x over previous
//
#include <hip/hip_runtime.h>

// Problem constants
#define TT    2048
#define NB    32
#define NL    10
#define NU    64
#define TTILE 64       // t per block (kernel 1)
#define UQ    16       // u per block (kernel 1)
#define SUBT  16       // t per scan sub-chunk
#define NSUB  4
#define NCHUNK 128     // TT/SUBT
#define NW    20       // iterated-sum words per (b,chunk,u)
#define DT    161      // d-tile row stride (floats); 161 mod 32 = 1 keeps scatter/scan <=2-way

typedef __attribute__((ext_vector_type(8))) short short8v;   // 8 bf16 (4 VGPRs)
typedef __attribute__((ext_vector_type(4))) float float4v;   // MFMA C/D

__device__ inline short f2bf(float f) {   // RNE float->bf16, returned as raw bits
    unsigned u = __float_as_uint(f);
    u += 0x7fffu + ((u >> 16) & 1u);
    return (short)(u >> 16);
}

// Chen composition C = A ∘ B over the 20-word alphabet:
// 0:(0) | 1:(1) 2:(2) 3:(12) | 4:(3) 5:(4) 6:(5) 7:(34) 8:(45) 9:(345)
// 10:(6) 11:(7) 12:(8) 13:(9) 14:(67) 15:(78) 16:(89) 17:(678) 18:(789) 19:(6789)
__device__ inline void chen_combine(const float* A, const float* B, float* C) {
    C[0]  = A[0] + B[0];
    C[1]  = A[1] + B[1];
    C[2]  = A[2] + B[2];
    C[3]  = A[3] + A[1]*B[2] + B[3];
    C[4]  = A[4] + B[4];
    C[5]  = A[5] + B[5];
    C[6]  = A[6] + B[6];
    C[7]  = A[7] + A[4]*B[5] + B[7];
    C[8]  = A[8] + A[5]*B[6] + B[8];
    C[9]  = A[9] + A[7]*B[6] + A[4]*B[8] + B[9];
    C[10] = A[10] + B[10];
    C[11] = A[11] + B[11];
    C[12] = A[12] + B[12];
    C[13] = A[13] + B[13];
    C[14] = A[14] + A[10]*B[11] + B[14];
    C[15] = A[15] + A[11]*B[12] + B[15];
    C[16] = A[16] + A[12]*B[13] + B[16];
    C[17] = A[17] + A[14]*B[12] + A[10]*B[15] + B[17];
    C[18] = A[18] + A[15]*B[13] + A[11]*B[16] + B[18];
    C[19] = A[19] + A[17]*B[13] + A[14]*B[16] + A[10]*B[18] + B[19];
}

// Kernel 1: per (b, t-tile, u-quarter): MFMA GEMM d = dX * K  ->  chunk iterated sums L
__global__ __launch_bounds__(256, 3)
void k_gemm_scan(const float* __restrict__ x, const float* __restrict__ K,
                 float* __restrict__ L) {
    __shared__ float sm[64 * DT];          // 10,304 floats = 41,216 B
    short* A_lds = (short*)sm;             // [8 regions][64 lanes][8]  = 8 KB
    short* B_lds = (short*)sm + 4096;      // [20 regions][64 lanes][8] = 20.5 KB
    float* dtile = sm;                     // aliased after MFMA: [t*DT + l*16 + ul]

    const int tid   = threadIdx.x;
    const int ttile = blockIdx.x;  // 0..31
    const int uq    = blockIdx.y;  // 0..3
    const int b     = blockIdx.z;  // 0..31
    const int t0    = ttile * TTILE;
    const int uh    = uq * UQ;
    const float dtc = 2.0f / (float)(TT - 1);

    // ---- stage A: dX (time-diffed x incl. time channel) as bf16 fragment tiles ----
    // region (w = t/16, s = f/32): element (lane, j) = dX[16w + (lane&15)][32s + (lane>>4)*8 + j]
    for (int it = tid; it < 512; it += 256) {        // 64 t-rows x 8 f-octets
        const int t = it >> 3, fq = it & 7;
        const int tg = t0 + t;
        const float* xp  = x + (size_t)(b * TT + tg) * 63;
        const float* xpm = xp - 63;
        short8v v;
#pragma unroll
        for (int j = 0; j < 8; ++j) {
            const int f = fq * 8 + j;
            float d;
            if (tg == 0)      d = 0.0f;
            else if (f < 63)  d = xp[f] - xpm[f];
            else              d = dtc;
            v[j] = f2bf(d);
        }
        const int w = t >> 4, m = t & 15, s = fq >> 2, qd = fq & 3;
        *(short8v*)&A_lds[((w * 2 + s) * 64 + qd * 16 + m) * 8] = v;
    }
    // ---- stage B: K slice as bf16 fragment tiles ----
    // region (nt = l, s): element (lane, j) = K[f=32s+(lane>>4)*8+j][l][uh + (lane&15)]
    for (int it = tid; it < 1280; it += 256) {       // 160 n-cols x 8 f-octets
        const int n = it % 160, fq = it / 160;
        const int l = n >> 4, ul = n & 15;
        const int s = fq >> 2, qd = fq & 3;
        const float* kp = K + (size_t)(8 * fq * NL + l) * NU + uh + ul;
        short8v v;
#pragma unroll
        for (int j = 0; j < 8; ++j) v[j] = f2bf(kp[(size_t)j * (NL * NU)]);
        *(short8v*)&B_lds[((l * 2 + s) * 64 + qd * 16 + ul) * 8] = v;
    }
    __syncthreads();

    // ---- MFMA: wave wv computes C rows [16wv,16wv+16) x 160 cols ----
    const int wv = tid >> 6, lane = tid & 63;
    const short8v* A8 = (const short8v*)A_lds;
    const short8v* B8 = (const short8v*)B_lds;
    const short8v a0 = A8[(wv * 2 + 0) * 64 + lane];
    const short8v a1 = A8[(wv * 2 + 1) * 64 + lane];
    float4v acc[10];
#pragma unroll
    for (int nt = 0; nt < 10; ++nt) {
        const short8v b0 = B8[(nt * 2 + 0) * 64 + lane];
        const short8v b1 = B8[(nt * 2 + 1) * 64 + lane];
        float4v z = {0.f, 0.f, 0.f, 0.f};
        z = __builtin_amdgcn_mfma_f32_16x16x32_bf16(a0, b0, z, 0, 0, 0);
        z = __builtin_amdgcn_mfma_f32_16x16x32_bf16(a1, b1, z, 0, 0, 0);
        acc[nt] = z;
    }
    __syncthreads();   // all frag reads done; safe to alias A/B region as d-tile

    // ---- scatter C -> dtile: col = nt*16 + (lane&15), row = (lane>>4)*4 + reg ----
    const int qd = lane >> 4, nl = lane & 15;
#pragma unroll
    for (int nt = 0; nt < 10; ++nt)
#pragma unroll
        for (int r = 0; r < 4; ++r)
            dtile[(wv * 16 + qd * 4 + r) * DT + nt * 16 + nl] = acc[nt][r];
    __syncthreads();

    // ---- chunk scan: wave = chain; lanes = 4 sub-chunks x 16 u ----
    const int sub = (tid >> 4) & 3;
    const int su  = tid & 15;
    float S[10];
#pragma unroll
    for (int i = 0; i < 10; ++i) S[i] = 0.0f;

    const int tstart = sub * SUBT;
    const float* dp = dtile + su;

    if (wv == 0) {
        for (int t = tstart; t < tstart + SUBT; ++t)
            S[0] += dp[t * DT + 0 * 16];
    } else if (wv == 1) {
        for (int t = tstart; t < tstart + SUBT; ++t) {
            const float d1 = dp[t * DT + 1 * 16];
            const float d2 = dp[t * DT + 2 * 16];
            S[2] += S[0] * d2;
            S[0] += d1;  S[1] += d2;
        }
    } else if (wv == 2) {
        for (int t = tstart; t < tstart + SUBT; ++t) {
            const float d3 = dp[t * DT + 3 * 16];
            const float d4 = dp[t * DT + 4 * 16];
            const float d5 = dp[t * DT + 5 * 16];
            S[5] += S[3] * d5;
            S[3] += S[0] * d4;
            S[4] += S[1] * d5;
            S[0] += d3;  S[1] += d4;  S[2] += d5;
        }
    } else {
        for (int t = tstart; t < tstart + SUBT; ++t) {
            const float d6 = dp[t * DT + 6 * 16];
            const float d7 = dp[t * DT + 7 * 16];
            const float d8 = dp[t * DT + 8 * 16];
            const float d9 = dp[t * DT + 9 * 16];
            S[9] += S[7] * d9;
            S[7] += S[4] * d8;
            S[8] += S[5] * d9;
            S[4] += S[0] * d7;
            S[5] += S[1] * d8;
            S[6] += S[2] * d9;
            S[0] += d6;  S[1] += d7;  S[2] += d8;  S[3] += d9;
        }
    }

    // ---- write the 20 words for (b, chunk, u) ----
    const int c = ttile * NSUB + sub;
    float* Lb = L + ((size_t)(b * NCHUNK + c) * NW) * NU + (uh + su);
    if (wv == 0) {
        Lb[0 * NU] = S[0];
    } else if (wv == 1) {
        Lb[1 * NU] = S[0];  Lb[2 * NU] = S[1];  Lb[3 * NU] = S[2];
    } else if (wv == 2) {
        Lb[4 * NU] = S[0];  Lb[5 * NU] = S[1];  Lb[6 * NU] = S[2];
        Lb[7 * NU] = S[3];  Lb[8 * NU] = S[4];  Lb[9 * NU] = S[5];
    } else {
        Lb[10 * NU] = S[0]; Lb[11 * NU] = S[1]; Lb[12 * NU] = S[2]; Lb[13 * NU] = S[3];
        Lb[14 * NU] = S[4]; Lb[15 * NU] = S[5]; Lb[16 * NU] = S[6];
        Lb[17 * NU] = S[7]; Lb[18 * NU] = S[8]; Lb[19 * NU] = S[9];
    }
}

// Kernel 2: fold 128 chunks via Chen. One block per b, 16 waves;
// wave q serially folds chunks [8q, 8q+8), then 4-level adjacent-pair tree via LDS.
__global__ __launch_bounds__(1024)
void k_fold(const float* __restrict__ L, float* __restrict__ out) {
    __shared__ float buf[8][NW][NU];    // 40,960 B
    const int b = blockIdx.x;
    const int u = threadIdx.x & 63;
    const int q = threadIdx.x >> 6;     // 0..15
    const float* Lb = L + (size_t)b * NCHUNK * NW * NU + u;

    float E[NW];
    {
        const float* p = Lb + (size_t)(q * 8) * NW * NU;
#pragma unroll
        for (int w = 0; w < NW; ++w) E[w] = p[w * NU];
    }
    for (int c = q * 8 + 1; c < q * 8 + 8; ++c) {
        const float* p = Lb + (size_t)c * NW * NU;
        float Bw[NW], Cw[NW];
#pragma unroll
        for (int w = 0; w < NW; ++w) Bw[w] = p[w * NU];
        chen_combine(E, Bw, Cw);
#pragma unroll
        for (int w = 0; w < NW; ++w) E[w] = Cw[w];
    }

#pragma unroll
    for (int lvl = 0; lvl < 4; ++lvl) {
        const int step = 1 << lvl;
        const bool active = (q & (step - 1)) == 0;
        const bool writer = active && ((q >> lvl) & 1);
        if (writer) {
            const int idx = (q - step) >> (lvl + 1);
#pragma unroll
            for (int w = 0; w < NW; ++w) buf[idx][w][u] = E[w];
        }
        __syncthreads();
        if (active && !writer) {
            const int idx = q >> (lvl + 1);
            float Bw[NW], Cw[NW];
#pragma unroll
            for (int w = 0; w < NW; ++w) Bw[w] = buf[idx][w][u];
            chen_combine(E, Bw, Cw);
#pragma unroll
            for (int w = 0; w < NW; ++w) E[w] = Cw[w];
        }
        __syncthreads();
    }
    if (q == 0) out[b * NU + u] = E[0] + E[3] + E[9] + E[19];
}

extern "C" void kernel_launch(void* const* d_in, const int* in_sizes, int n_in,
                              void* d_out, int out_size, void* d_ws, size_t ws_size,
                              hipStream_t stream) {
    const float* x = (const float*)d_in[0];   // (32, 2048, 63) fp32
    const float* K = (const float*)d_in[1];   // (64, 10, 64)  fp32
    float* out = (float*)d_out;               // (32, 64) fp32
    float* L   = (float*)d_ws;                // 32*128*20*64*4 = 20,971,520 B

    dim3 g1(TT / TTILE, NU / UQ, NB);         // (32, 4, 32)
    k_gemm_scan<<<g1, 256, 0, stream>>>(x, K, L);
    k_fold<<<NB, 1024, 0, stream>>>(L, out);
}

// Round 4
// 90.656 us; speedup vs baseline: 2.6690x; 1.5086x over previous
//
#include <hip/hip_runtime.h>

// Problem constants
#define TT     2048
#define NB     32
#define NL     10
#define NU     64
#define TTILE  64
#define NTTILE 32          // TT/TTILE = chunk count after in-block fold
#define NW     20          // iterated-sum words per (b,chunk,u)
#define DT2    145         // d-tile row stride (cols 144 = l=1..9 x 16; odd -> conflict-free scan)

// d_ws layout (bytes):
//   Ag: [b][ttile][reg(8)][lane(64)][8] bf16   = 8 MB      @ 0
//   Bg: [uq(4)][reg(20)][lane(64)][8] bf16     = 80 KB     @ 8 MB
//   L : [b][chunk(32)][w(20)][u(64)] fp32      = 5.24 MB   @ 8 MB + 128 KB
#define BG_OFF (8u * 1024u * 1024u)
#define L_OFF  (BG_OFF + 128u * 1024u)

typedef __attribute__((ext_vector_type(8))) short short8v;   // 8 bf16
typedef __attribute__((ext_vector_type(4))) float float4v;   // MFMA C/D
typedef __attribute__((address_space(3))) char lds_char;
typedef __attribute__((address_space(1))) const char g_char;

__device__ inline short f2bf(float f) {   // RNE float->bf16 raw bits
    unsigned u = __float_as_uint(f);
    u += 0x7fffu + ((u >> 16) & 1u);
    return (short)(u >> 16);
}

// ---- Chen composition (full 20-word alphabet), C = A(earlier) ∘ B(later) ----
// 0:(0) | 1:(1) 2:(2) 3:(12) | 4:(3) 5:(4) 6:(5) 7:(34) 8:(45) 9:(345)
// 10:(6) 11:(7) 12:(8) 13:(9) 14:(67) 15:(78) 16:(89) 17:(678) 18:(789) 19:(6789)
__device__ inline void chen_combine(const float* A, const float* B, float* C) {
    C[0]  = A[0] + B[0];
    C[1]  = A[1] + B[1];
    C[2]  = A[2] + B[2];
    C[3]  = A[3] + A[1]*B[2] + B[3];
    C[4]  = A[4] + B[4];
    C[5]  = A[5] + B[5];
    C[6]  = A[6] + B[6];
    C[7]  = A[7] + A[4]*B[5] + B[7];
    C[8]  = A[8] + A[5]*B[6] + B[8];
    C[9]  = A[9] + A[7]*B[6] + A[4]*B[8] + B[9];
    C[10] = A[10] + B[10];
    C[11] = A[11] + B[11];
    C[12] = A[12] + B[12];
    C[13] = A[13] + B[13];
    C[14] = A[14] + A[10]*B[11] + B[14];
    C[15] = A[15] + A[11]*B[12] + B[15];
    C[16] = A[16] + A[12]*B[13] + B[16];
    C[17] = A[17] + A[14]*B[12] + A[10]*B[15] + B[17];
    C[18] = A[18] + A[15]*B[13] + A[11]*B[16] + B[18];
    C[19] = A[19] + A[17]*B[13] + A[14]*B[16] + A[10]*B[18] + B[19];
}

// ---- chain-local Chen combiners (words within one chain group) ----
struct Chen1 {  // S0=(1) S1=(2) S2=(12)
    __device__ void operator()(const float* A, const float* B, float* C) const {
        C[2] = A[2] + A[0]*B[1] + B[2];
        C[0] = A[0] + B[0];  C[1] = A[1] + B[1];
    }
};
struct Chen2 {  // S0=(3) S1=(4) S2=(5) S3=(34) S4=(45) S5=(345)
    __device__ void operator()(const float* A, const float* B, float* C) const {
        C[5] = A[5] + A[3]*B[2] + A[0]*B[4] + B[5];
        C[3] = A[3] + A[0]*B[1] + B[3];
        C[4] = A[4] + A[1]*B[2] + B[4];
        C[0] = A[0] + B[0];  C[1] = A[1] + B[1];  C[2] = A[2] + B[2];
    }
};
struct Chen3 {  // S0..3=(6)(7)(8)(9) S4=(67) S5=(78) S6=(89) S7=(678) S8=(789) S9=(6789)
    __device__ void operator()(const float* A, const float* B, float* C) const {
        C[9] = A[9] + A[7]*B[3] + A[4]*B[6] + A[0]*B[8] + B[9];
        C[7] = A[7] + A[4]*B[2] + A[0]*B[5] + B[7];
        C[8] = A[8] + A[5]*B[3] + A[1]*B[6] + B[8];
        C[4] = A[4] + A[0]*B[1] + B[4];
        C[5] = A[5] + A[1]*B[2] + B[5];
        C[6] = A[6] + A[2]*B[3] + B[6];
        C[0] = A[0] + B[0];  C[1] = A[1] + B[1];
        C[2] = A[2] + B[2];  C[3] = A[3] + B[3];
    }
};

// Cross-lane fold of 4 sub-chunks (sub = lane>>4) in t-order via xor-16/32 tree.
template <int N, typename CH>
__device__ inline void wave_fold(float* S, int sub, CH chen) {
    float O[N], A[N], Bv[N], C[N];
#pragma unroll
    for (int w = 0; w < N; ++w) O[w] = __shfl_xor(S[w], 16);
    {
        const bool e = (sub & 1) == 0;
#pragma unroll
        for (int w = 0; w < N; ++w) { A[w] = e ? S[w] : O[w]; Bv[w] = e ? O[w] : S[w]; }
        chen(A, Bv, C);
    }
#pragma unroll
    for (int w = 0; w < N; ++w) O[w] = __shfl_xor(C[w], 32);
    {
        const bool e = (sub & 2) == 0;
#pragma unroll
        for (int w = 0; w < N; ++w) { A[w] = e ? C[w] : O[w]; Bv[w] = e ? O[w] : C[w]; }
        chen(A, Bv, S);
    }
}

// Kernel 0: convert x -> dX bf16 fragment tiles (Ag) and K -> bf16 fragment tiles (Bg)
__global__ __launch_bounds__(256)
void k_prep(const float* __restrict__ x, const float* __restrict__ K,
            short* __restrict__ Ag, short* __restrict__ Bg) {
    const int tid = threadIdx.x;
    const int blk = blockIdx.x;
    const float dtc = 2.0f / (float)(TT - 1);
    if (blk < NB * NTTILE) {
        const int b = blk >> 5, tt = blk & 31;
        const int t0 = tt * TTILE;
        short* out = Ag + (size_t)blk * 4096;
#pragma unroll
        for (int i = 0; i < 2; ++i) {
            const int e = i * 256 + tid;            // 0..511
            const int lane = e & 63, reg = e >> 6;  // reg = w*2+s
            const int w = reg >> 1, s = reg & 1;
            const int t = w * 16 + (lane & 15);
            const int f0 = s * 32 + (lane >> 4) * 8;
            const int tg = t0 + t;
            short8v v;
            if (tg == 0) {
#pragma unroll
                for (int j = 0; j < 8; ++j) v[j] = 0;
            } else {
                const float* xp = x + (size_t)(b * TT + tg) * 63;
#pragma unroll
                for (int j = 0; j < 8; ++j) {
                    const int f = f0 + j;
                    v[j] = f2bf(f < 63 ? xp[f] - xp[f - 63] : dtc);
                }
            }
            *(short8v*)(out + (size_t)e * 8) = v;
        }
    } else {
        const int kb = blk - NB * NTTILE;           // 0..7
#pragma unroll
        for (int it = 0; it < 3; ++it) {
            const int r = it * 256 + tid;
            if (r >= 640) break;
            const int idx = kb * 640 + r;           // short8v index 0..5119
            const int lane = idx & 63, r20 = (idx >> 6) % 20, uq = (idx >> 6) / 20;
            const int l = r20 >> 1, s = r20 & 1;
            const int f0 = s * 32 + (lane >> 4) * 8;
            const int u = uq * 16 + (lane & 15);
            short8v v;
#pragma unroll
            for (int j = 0; j < 8; ++j)
                v[j] = f2bf(K[(size_t)(f0 + j) * (NL * NU) + l * NU + u]);
            *(short8v*)(Bg + (size_t)idx * 8) = v;
        }
    }
}

// Kernel 1: DMA-stage fragments -> MFMA d = dX*K -> scan chains -> in-block Chen fold
__global__ __launch_bounds__(256, 4)
void k_gemm_scan(const short* __restrict__ Ag, const short* __restrict__ Bg,
                 float* __restrict__ L) {
    __shared__ __align__(16) float sm[64 * DT2 + 64];   // 37,376 B -> 4 blocks/CU
    short* A_lds = (short*)sm;          // [8][64][8] = 8 KB
    short* B_lds = (short*)sm + 4096;   // [20][64][8] = 20 KB
    float* dtile = sm;                  // alias post-MFMA: [t*145 + (l-1)*16 + su]
    float* w0buf = sm + 64 * DT2;       // [4][16]

    const int tid   = threadIdx.x;
    const int ttile = blockIdx.x;  // 0..31
    const int uq    = blockIdx.y;  // 0..3
    const int b     = blockIdx.z;  // 0..31
    const int wv    = tid >> 6, lane = tid & 63;

    // ---- async DMA stage: A 8 KB (2 rounds), B 20 KB (5 rounds) ----
    {
        const char* ga = (const char*)(Ag + (size_t)(b * NTTILE + ttile) * 4096);
#pragma unroll
        for (int i = 0; i < 2; ++i) {
            const int e = i * 256 + tid;
            __builtin_amdgcn_global_load_lds((g_char*)(ga + e * 16),
                                             (lds_char*)((char*)A_lds + e * 16), 16, 0, 0);
        }
        const char* gb = (const char*)(Bg + (size_t)uq * 10240);
#pragma unroll
        for (int i = 0; i < 5; ++i) {
            const int e = i * 256 + tid;
            __builtin_amdgcn_global_load_lds((g_char*)(gb + e * 16),
                                             (lds_char*)((char*)B_lds + e * 16), 16, 0, 0);
        }
    }
    __syncthreads();

    // ---- MFMA: wave wv computes C rows [16wv,16wv+16) x 160 cols ----
    const short8v* A8 = (const short8v*)A_lds;
    const short8v* B8 = (const short8v*)B_lds;
    const short8v a0 = A8[(wv * 2 + 0) * 64 + lane];
    const short8v a1 = A8[(wv * 2 + 1) * 64 + lane];
    float4v acc[10];
#pragma unroll
    for (int nt = 0; nt < 10; ++nt) {
        const short8v b0 = B8[(nt * 2 + 0) * 64 + lane];
        const short8v b1 = B8[(nt * 2 + 1) * 64 + lane];
        float4v z = {0.f, 0.f, 0.f, 0.f};
        z = __builtin_amdgcn_mfma_f32_16x16x32_bf16(a0, b0, z, 0, 0, 0);
        z = __builtin_amdgcn_mfma_f32_16x16x32_bf16(a1, b1, z, 0, 0, 0);
        acc[nt] = z;
    }

    // ---- word (0): reduce acc[0] over reg + qd lanes (chain 0 never hits LDS) ----
    float s0 = acc[0][0] + acc[0][1] + acc[0][2] + acc[0][3];
    s0 += __shfl_xor(s0, 16);
    s0 += __shfl_xor(s0, 32);
    if (lane < 16) w0buf[wv * 16 + lane] = s0;   // disjoint from staging region
    __syncthreads();   // frag reads done -> dtile aliasing safe; w0buf visible

    // ---- scatter C (l=1..9) -> dtile ----
    const int qd = lane >> 4, nl = lane & 15;
#pragma unroll
    for (int nt = 1; nt < 10; ++nt)
#pragma unroll
        for (int r = 0; r < 4; ++r)
            dtile[(wv * 16 + qd * 4 + r) * DT2 + (nt - 1) * 16 + nl] = acc[nt][r];
    __syncthreads();

    // ---- scan: wave = chain; lanes = 4 sub-chunks x 16 u ----
    const int sub = (tid >> 4) & 3;
    const int su  = tid & 15;
    const float* dp = dtile + su;
    const int tb = sub * 16;
    float S[10];
#pragma unroll
    for (int i = 0; i < 10; ++i) S[i] = 0.0f;

    float* Lb = L + ((size_t)(b * NTTILE + ttile) * NW) * NU + uq * 16 + su;

    if (wv == 0) {            // chain 1: l=1,2 -> col offs 0,16
        for (int t = tb; t < tb + 16; ++t) {
            const float d1 = dp[t * DT2 + 0];
            const float d2 = dp[t * DT2 + 16];
            S[2] += S[0] * d2;
            S[0] += d1;  S[1] += d2;
        }
        wave_fold<3>(S, sub, Chen1());
        if (sub == 0) { Lb[1*NU] = S[0];  Lb[2*NU] = S[1];  Lb[3*NU] = S[2]; }
    } else if (wv == 1) {     // chain 2: l=3,4,5 -> 32,48,64
        for (int t = tb; t < tb + 16; ++t) {
            const float d3 = dp[t * DT2 + 32];
            const float d4 = dp[t * DT2 + 48];
            const float d5 = dp[t * DT2 + 64];
            S[5] += S[3] * d5;
            S[3] += S[0] * d4;
            S[4] += S[1] * d5;
            S[0] += d3;  S[1] += d4;  S[2] += d5;
        }
        wave_fold<6>(S, sub, Chen2());
        if (sub == 0) {
            Lb[4*NU] = S[0];  Lb[5*NU] = S[1];  Lb[6*NU] = S[2];
            Lb[7*NU] = S[3];  Lb[8*NU] = S[4];  Lb[9*NU] = S[5];
        }
    } else if (wv == 2) {     // chain 3: l=6..9 -> 80,96,112,128
        for (int t = tb; t < tb + 16; ++t) {
            const float d6 = dp[t * DT2 + 80];
            const float d7 = dp[t * DT2 + 96];
            const float d8 = dp[t * DT2 + 112];
            const float d9 = dp[t * DT2 + 128];
            S[9] += S[7] * d9;
            S[7] += S[4] * d8;
            S[8] += S[5] * d9;
            S[4] += S[0] * d7;
            S[5] += S[1] * d8;
            S[6] += S[2] * d9;
            S[0] += d6;  S[1] += d7;  S[2] += d8;  S[3] += d9;
        }
        wave_fold<10>(S, sub, Chen3());
        if (sub == 0) {
            Lb[10*NU] = S[0]; Lb[11*NU] = S[1]; Lb[12*NU] = S[2]; Lb[13*NU] = S[3];
            Lb[14*NU] = S[4]; Lb[15*NU] = S[5]; Lb[16*NU] = S[6];
            Lb[17*NU] = S[7]; Lb[18*NU] = S[8]; Lb[19*NU] = S[9];
        }
    } else {                  // wave 3: finalize word (0)
        if (lane < 16) {
            const float w0 = w0buf[lane] + w0buf[16 + lane] + w0buf[32 + lane] + w0buf[48 + lane];
            Lb[0] = w0;       // su == lane here
        }
    }
}

// Kernel 2: fold 32 chunks per b. 4 waves x 8 serial chunks + 2-level LDS tree.
__global__ __launch_bounds__(256)
void k_fold(const float* __restrict__ L, float* __restrict__ out) {
    __shared__ float buf[2][NW][NU];    // 10,240 B
    const int b = blockIdx.x;
    const int u = threadIdx.x & 63;
    const int q = threadIdx.x >> 6;     // 0..3
    const float* Lb = L + (size_t)b * NTTILE * NW * NU + u;

    float E[NW];
    {
        const float* p = Lb + (size_t)(q * 8) * NW * NU;
#pragma unroll
        for (int w = 0; w < NW; ++w) E[w] = p[w * NU];
    }
    for (int c = q * 8 + 1; c < q * 8 + 8; ++c) {
        const float* p = Lb + (size_t)c * NW * NU;
        float Bw[NW], Cw[NW];
#pragma unroll
        for (int w = 0; w < NW; ++w) Bw[w] = p[w * NU];
        chen_combine(E, Bw, Cw);
#pragma unroll
        for (int w = 0; w < NW; ++w) E[w] = Cw[w];
    }

    if (q & 1) {                        // q=1 -> buf[0], q=3 -> buf[1]
#pragma unroll
        for (int w = 0; w < NW; ++w) buf[(q - 1) >> 1][w][u] = E[w];
    }
    __syncthreads();
    if (!(q & 1)) {                     // q=0 <- buf[0], q=2 <- buf[1]
        float Bw[NW], Cw[NW];
#pragma unroll
        for (int w = 0; w < NW; ++w) Bw[w] = buf[q >> 1][w][u];
        chen_combine(E, Bw, Cw);
#pragma unroll
        for (int w = 0; w < NW; ++w) E[w] = Cw[w];
    }
    __syncthreads();
    if (q == 2) {
#pragma unroll
        for (int w = 0; w < NW; ++w) buf[0][w][u] = E[w];
    }
    __syncthreads();
    if (q == 0) {
        float Bw[NW], Cw[NW];
#pragma unroll
        for (int w = 0; w < NW; ++w) Bw[w] = buf[0][w][u];
        chen_combine(E, Bw, Cw);
        out[b * NU + u] = Cw[0] + Cw[3] + Cw[9] + Cw[19];
    }
}

extern "C" void kernel_launch(void* const* d_in, const int* in_sizes, int n_in,
                              void* d_out, int out_size, void* d_ws, size_t ws_size,
                              hipStream_t stream) {
    const float* x = (const float*)d_in[0];   // (32, 2048, 63) fp32
    const float* K = (const float*)d_in[1];   // (64, 10, 64)  fp32
    float* out = (float*)d_out;               // (32, 64) fp32
    short* Ag = (short*)d_ws;
    short* Bg = (short*)((char*)d_ws + BG_OFF);
    float* L  = (float*)((char*)d_ws + L_OFF);   // total ws use ~13.5 MB

    k_prep<<<NB * NTTILE + 8, 256, 0, stream>>>(x, K, Ag, Bg);
    dim3 g1(NTTILE, 4, NB);                   // (32, 4, 32)
    k_gemm_scan<<<g1, 256, 0, stream>>>(Ag, Bg, L);
    k_fold<<<NB, 256, 0, stream>>>(L, out);
}

// Round 5
// 89.349 us; speedup vs baseline: 2.7081x; 1.0146x over previous
//
#include <hip/hip_runtime.h>

// Problem constants
#define TT     2048
#define NB     32
#define NL     10
#define NU     64
#define TTILE  64
#define NTTILE 32          // TT/TTILE = chunk count after in-block fold
#define NW     20          // iterated-sum words per (b,chunk,u)
#define DT2    145         // d-tile row stride (cols 144 = l=1..9 x 16; odd -> conflict-free)

// d_ws layout (bytes):
//   Ag: [b][ttile][reg(8)][lane(64)][8] bf16   = 8 MB      @ 0
//   Bg: [uq(4)][reg(20)][lane(64)][8] bf16     = 80 KB     @ 8 MB
//   L : [b][chunk(32)][w(20)][u(64)] fp32      = 5.24 MB   @ 8 MB + 128 KB
#define BG_OFF (8u * 1024u * 1024u)
#define L_OFF  (BG_OFF + 128u * 1024u)

typedef __attribute__((ext_vector_type(8))) short short8v;   // 8 bf16
typedef __attribute__((ext_vector_type(4))) float float4v;   // MFMA C/D
typedef __attribute__((address_space(3))) char lds_char;
typedef __attribute__((address_space(1))) const char g_char;

__device__ inline short f2bf(float f) {   // RNE float->bf16 raw bits
    unsigned u = __float_as_uint(f);
    u += 0x7fffu + ((u >> 16) & 1u);
    return (short)(u >> 16);
}

// ---- Chen composition (full 20-word alphabet), C = A(earlier) ∘ B(later) ----
// 0:(0) | 1:(1) 2:(2) 3:(12) | 4:(3) 5:(4) 6:(5) 7:(34) 8:(45) 9:(345)
// 10:(6) 11:(7) 12:(8) 13:(9) 14:(67) 15:(78) 16:(89) 17:(678) 18:(789) 19:(6789)
__device__ inline void chen_combine(const float* A, const float* B, float* C) {
    C[0]  = A[0] + B[0];
    C[1]  = A[1] + B[1];
    C[2]  = A[2] + B[2];
    C[3]  = A[3] + A[1]*B[2] + B[3];
    C[4]  = A[4] + B[4];
    C[5]  = A[5] + B[5];
    C[6]  = A[6] + B[6];
    C[7]  = A[7] + A[4]*B[5] + B[7];
    C[8]  = A[8] + A[5]*B[6] + B[8];
    C[9]  = A[9] + A[7]*B[6] + A[4]*B[8] + B[9];
    C[10] = A[10] + B[10];
    C[11] = A[11] + B[11];
    C[12] = A[12] + B[12];
    C[13] = A[13] + B[13];
    C[14] = A[14] + A[10]*B[11] + B[14];
    C[15] = A[15] + A[11]*B[12] + B[15];
    C[16] = A[16] + A[12]*B[13] + B[16];
    C[17] = A[17] + A[14]*B[12] + A[10]*B[15] + B[17];
    C[18] = A[18] + A[15]*B[13] + A[11]*B[16] + B[18];
    C[19] = A[19] + A[17]*B[13] + A[14]*B[16] + A[10]*B[18] + B[19];
}

// ---- chain-local Chen combiners ----
struct Chen1 {  // S0=(1) S1=(2) S2=(12)
    __device__ void operator()(const float* A, const float* B, float* C) const {
        C[2] = A[2] + A[0]*B[1] + B[2];
        C[0] = A[0] + B[0];  C[1] = A[1] + B[1];
    }
};
struct Chen2 {  // S0=(3) S1=(4) S2=(5) S3=(34) S4=(45) S5=(345)
    __device__ void operator()(const float* A, const float* B, float* C) const {
        C[5] = A[5] + A[3]*B[2] + A[0]*B[4] + B[5];
        C[3] = A[3] + A[0]*B[1] + B[3];
        C[4] = A[4] + A[1]*B[2] + B[4];
        C[0] = A[0] + B[0];  C[1] = A[1] + B[1];  C[2] = A[2] + B[2];
    }
};
struct Chen3 {  // S0..3=(6)(7)(8)(9) S4=(67) S5=(78) S6=(89) S7=(678) S8=(789) S9=(6789)
    __device__ void operator()(const float* A, const float* B, float* C) const {
        C[9] = A[9] + A[7]*B[3] + A[4]*B[6] + A[0]*B[8] + B[9];
        C[7] = A[7] + A[4]*B[2] + A[0]*B[5] + B[7];
        C[8] = A[8] + A[5]*B[3] + A[1]*B[6] + B[8];
        C[4] = A[4] + A[0]*B[1] + B[4];
        C[5] = A[5] + A[1]*B[2] + B[5];
        C[6] = A[6] + A[2]*B[3] + B[6];
        C[0] = A[0] + B[0];  C[1] = A[1] + B[1];
        C[2] = A[2] + B[2];  C[3] = A[3] + B[3];
    }
};

// Cross-lane fold of 4 sub-chunks (sub = lane>>4) in t-order via xor-16/32 tree.
template <int N, typename CH>
__device__ inline void wave_fold(float* S, int sub, CH chen) {
    float O[N], A[N], Bv[N], C[N];
#pragma unroll
    for (int w = 0; w < N; ++w) O[w] = __shfl_xor(S[w], 16);
    {
        const bool e = (sub & 1) == 0;
#pragma unroll
        for (int w = 0; w < N; ++w) { A[w] = e ? S[w] : O[w]; Bv[w] = e ? O[w] : S[w]; }
        chen(A, Bv, C);
    }
#pragma unroll
    for (int w = 0; w < N; ++w) O[w] = __shfl_xor(C[w], 32);
    {
        const bool e = (sub & 2) == 0;
#pragma unroll
        for (int w = 0; w < N; ++w) { A[w] = e ? C[w] : O[w]; Bv[w] = e ? O[w] : C[w]; }
        chen(A, Bv, S);
    }
}

// Kernel 0: x -> dX bf16 fragment tiles (Ag), K -> bf16 fragment tiles (Bg).
// A-blocks stage the contiguous 65x63-float x-tile in LDS (coalesced linear
// loads), then build fragments from LDS; 63-stride is odd -> conflict-light.
__global__ __launch_bounds__(256)
void k_prep(const float* __restrict__ x, const float* __restrict__ K,
            short* __restrict__ Ag, short* __restrict__ Bg) {
    __shared__ float xs[65 * 63];        // 16,380 B
    const int tid = threadIdx.x;
    const int blk = blockIdx.x;
    const float dtc = 2.0f / (float)(TT - 1);
    if (blk < NB * NTTILE) {
        const int b = blk >> 5, tt = blk & 31;
        const int t0 = tt * TTILE;
        // stage rows (t0-1 .. t0+63) -> xs[r*63+f], r = t - (t0-1)
        if (tt > 0) {
            const float* src = x + (size_t)(b * TT + t0 - 1) * 63;
            for (int i = tid; i < 65 * 63; i += 256) xs[i] = src[i];
        } else {
            const float* src = x + (size_t)b * TT * 63;    // rows 0..63 -> r=1..64
            for (int i = tid; i < 64 * 63; i += 256) xs[63 + i] = src[i];
        }
        __syncthreads();

        short* out = Ag + (size_t)blk * 4096;
#pragma unroll
        for (int i = 0; i < 2; ++i) {
            const int e = i * 256 + tid;            // 0..511
            const int lane = e & 63, reg = e >> 6;  // reg = w*2+s
            const int w = reg >> 1, s = reg & 1;
            const int t = w * 16 + (lane & 15);
            const int f0 = s * 32 + (lane >> 4) * 8;
            short8v v;
            if (t0 + t == 0) {
#pragma unroll
                for (int j = 0; j < 8; ++j) v[j] = 0;
            } else {
                const float* hi = xs + (t + 1) * 63;
                const float* lo = xs + t * 63;
#pragma unroll
                for (int j = 0; j < 8; ++j) {
                    const int f = f0 + j;
                    v[j] = f2bf(f < 63 ? hi[f] - lo[f] : dtc);
                }
            }
            *(short8v*)(out + (size_t)e * 8) = v;
        }
    } else {
        const int kb = blk - NB * NTTILE;           // 0..7
#pragma unroll
        for (int it = 0; it < 3; ++it) {
            const int r = it * 256 + tid;
            if (r >= 640) break;
            const int idx = kb * 640 + r;           // short8v index 0..5119
            const int lane = idx & 63, r20 = (idx >> 6) % 20, uq = (idx >> 6) / 20;
            const int l = r20 >> 1, s = r20 & 1;
            const int f0 = s * 32 + (lane >> 4) * 8;
            const int u = uq * 16 + (lane & 15);
            short8v v;
#pragma unroll
            for (int j = 0; j < 8; ++j)
                v[j] = f2bf(K[(size_t)(f0 + j) * (NL * NU) + l * NU + u]);
            *(short8v*)(Bg + (size_t)idx * 8) = v;
        }
    }
}

// Kernel 1: DMA-stage fragments -> MFMA d = dX*K -> scan chains -> in-block Chen fold
__global__ __launch_bounds__(256, 4)
void k_gemm_scan(const short* __restrict__ Ag, const short* __restrict__ Bg,
                 float* __restrict__ L) {
    __shared__ __align__(16) float sm[64 * DT2 + 64];   // 37,376 B -> 4 blocks/CU
    short* A_lds = (short*)sm;          // [8][64][8] = 8 KB
    short* B_lds = (short*)sm + 4096;   // [20][64][8] = 20 KB
    float* dtile = sm;                  // alias post-MFMA: [t*145 + (l-1)*16 + su]
    float* w0buf = sm + 64 * DT2;       // [4][16]

    const int tid   = threadIdx.x;
    const int ttile = blockIdx.x;
    const int uq    = blockIdx.y;
    const int b     = blockIdx.z;
    const int wv    = tid >> 6, lane = tid & 63;

    // ---- async DMA stage: A 8 KB, B 20 KB ----
    {
        const char* ga = (const char*)(Ag + (size_t)(b * NTTILE + ttile) * 4096);
#pragma unroll
        for (int i = 0; i < 2; ++i) {
            const int e = i * 256 + tid;
            __builtin_amdgcn_global_load_lds((g_char*)(ga + e * 16),
                                             (lds_char*)((char*)A_lds + e * 16), 16, 0, 0);
        }
        const char* gb = (const char*)(Bg + (size_t)uq * 10240);
#pragma unroll
        for (int i = 0; i < 5; ++i) {
            const int e = i * 256 + tid;
            __builtin_amdgcn_global_load_lds((g_char*)(gb + e * 16),
                                             (lds_char*)((char*)B_lds + e * 16), 16, 0, 0);
        }
    }
    __syncthreads();

    // ---- MFMA: wave wv computes C rows [16wv,16wv+16) x 160 cols ----
    const short8v* A8 = (const short8v*)A_lds;
    const short8v* B8 = (const short8v*)B_lds;
    const short8v a0 = A8[(wv * 2 + 0) * 64 + lane];
    const short8v a1 = A8[(wv * 2 + 1) * 64 + lane];
    float4v acc[10];
#pragma unroll
    for (int nt = 0; nt < 10; ++nt) {
        const short8v b0 = B8[(nt * 2 + 0) * 64 + lane];
        const short8v b1 = B8[(nt * 2 + 1) * 64 + lane];
        float4v z = {0.f, 0.f, 0.f, 0.f};
        z = __builtin_amdgcn_mfma_f32_16x16x32_bf16(a0, b0, z, 0, 0, 0);
        z = __builtin_amdgcn_mfma_f32_16x16x32_bf16(a1, b1, z, 0, 0, 0);
        acc[nt] = z;
    }

    // ---- word (0): reduce acc[0] (chain 0 never hits LDS) ----
    float s0 = acc[0][0] + acc[0][1] + acc[0][2] + acc[0][3];
    s0 += __shfl_xor(s0, 16);
    s0 += __shfl_xor(s0, 32);
    if (lane < 16) w0buf[wv * 16 + lane] = s0;
    __syncthreads();

    // ---- scatter C (l=1..9) -> dtile ----
    const int qd = lane >> 4, nl = lane & 15;
#pragma unroll
    for (int nt = 1; nt < 10; ++nt)
#pragma unroll
        for (int r = 0; r < 4; ++r)
            dtile[(wv * 16 + qd * 4 + r) * DT2 + (nt - 1) * 16 + nl] = acc[nt][r];
    __syncthreads();

    // ---- scan: wave = chain; lanes = 4 sub-chunks x 16 u ----
    const int sub = (tid >> 4) & 3;
    const int su  = tid & 15;
    const float* dp = dtile + su;
    const int tb = sub * 16;
    float S[10];
#pragma unroll
    for (int i = 0; i < 10; ++i) S[i] = 0.0f;

    float* Lb = L + ((size_t)(b * NTTILE + ttile) * NW) * NU + uq * 16 + su;

    if (wv == 0) {            // chain 1: l=1,2 -> col offs 0,16
        for (int t = tb; t < tb + 16; ++t) {
            const float d1 = dp[t * DT2 + 0];
            const float d2 = dp[t * DT2 + 16];
            S[2] += S[0] * d2;
            S[0] += d1;  S[1] += d2;
        }
        wave_fold<3>(S, sub, Chen1());
        if (sub == 0) { Lb[1*NU] = S[0];  Lb[2*NU] = S[1];  Lb[3*NU] = S[2]; }
    } else if (wv == 1) {     // chain 2: l=3,4,5 -> 32,48,64
        for (int t = tb; t < tb + 16; ++t) {
            const float d3 = dp[t * DT2 + 32];
            const float d4 = dp[t * DT2 + 48];
            const float d5 = dp[t * DT2 + 64];
            S[5] += S[3] * d5;
            S[3] += S[0] * d4;
            S[4] += S[1] * d5;
            S[0] += d3;  S[1] += d4;  S[2] += d5;
        }
        wave_fold<6>(S, sub, Chen2());
        if (sub == 0) {
            Lb[4*NU] = S[0];  Lb[5*NU] = S[1];  Lb[6*NU] = S[2];
            Lb[7*NU] = S[3];  Lb[8*NU] = S[4];  Lb[9*NU] = S[5];
        }
    } else if (wv == 2) {     // chain 3: l=6..9 -> 80,96,112,128
        for (int t = tb; t < tb + 16; ++t) {
            const float d6 = dp[t * DT2 + 80];
            const float d7 = dp[t * DT2 + 96];
            const float d8 = dp[t * DT2 + 112];
            const float d9 = dp[t * DT2 + 128];
            S[9] += S[7] * d9;
            S[7] += S[4] * d8;
            S[8] += S[5] * d9;
            S[4] += S[0] * d7;
            S[5] += S[1] * d8;
            S[6] += S[2] * d9;
            S[0] += d6;  S[1] += d7;  S[2] += d8;  S[3] += d9;
        }
        wave_fold<10>(S, sub, Chen3());
        if (sub == 0) {
            Lb[10*NU] = S[0]; Lb[11*NU] = S[1]; Lb[12*NU] = S[2]; Lb[13*NU] = S[3];
            Lb[14*NU] = S[4]; Lb[15*NU] = S[5]; Lb[16*NU] = S[6];
            Lb[17*NU] = S[7]; Lb[18*NU] = S[8]; Lb[19*NU] = S[9];
        }
    } else {                  // wave 3: finalize word (0)
        if (lane < 16) {
            const float w0 = w0buf[lane] + w0buf[16 + lane] + w0buf[32 + lane] + w0buf[48 + lane];
            Lb[0] = w0;
        }
    }
}

// Kernel 2: fold 32 chunks per b. 8 waves x 4 serial chunks + 3-level LDS tree.
__global__ __launch_bounds__(512)
void k_fold(const float* __restrict__ L, float* __restrict__ out) {
    __shared__ float buf[4][NW][NU];    // 20,480 B
    const int b = blockIdx.x;
    const int u = threadIdx.x & 63;
    const int q = threadIdx.x >> 6;     // 0..7
    const float* Lb = L + (size_t)b * NTTILE * NW * NU + u;

    float E[NW];
    {
        const float* p = Lb + (size_t)(q * 4) * NW * NU;
#pragma unroll
        for (int w = 0; w < NW; ++w) E[w] = p[w * NU];
    }
    for (int c = q * 4 + 1; c < q * 4 + 4; ++c) {
        const float* p = Lb + (size_t)c * NW * NU;
        float Bw[NW], Cw[NW];
#pragma unroll
        for (int w = 0; w < NW; ++w) Bw[w] = p[w * NU];
        chen_combine(E, Bw, Cw);
#pragma unroll
        for (int w = 0; w < NW; ++w) E[w] = Cw[w];
    }

#pragma unroll
    for (int lvl = 0; lvl < 3; ++lvl) {
        const int step = 1 << lvl;
        const bool active = (q & (step - 1)) == 0;
        const bool writer = active && ((q >> lvl) & 1);
        if (writer) {
            const int idx = (q - step) >> (lvl + 1);
#pragma unroll
            for (int w = 0; w < NW; ++w) buf[idx][w][u] = E[w];
        }
        __syncthreads();
        if (active && !writer) {
            const int idx = q >> (lvl + 1);
            float Bw[NW], Cw[NW];
#pragma unroll
            for (int w = 0; w < NW; ++w) Bw[w] = buf[idx][w][u];
            chen_combine(E, Bw, Cw);
#pragma unroll
            for (int w = 0; w < NW; ++w) E[w] = Cw[w];
        }
        __syncthreads();
    }
    if (q == 0) out[b * NU + u] = E[0] + E[3] + E[9] + E[19];
}

extern "C" void kernel_launch(void* const* d_in, const int* in_sizes, int n_in,
                              void* d_out, int out_size, void* d_ws, size_t ws_size,
                              hipStream_t stream) {
    const float* x = (const float*)d_in[0];   // (32, 2048, 63) fp32
    const float* K = (const float*)d_in[1];   // (64, 10, 64)  fp32
    float* out = (float*)d_out;               // (32, 64) fp32
    short* Ag = (short*)d_ws;
    short* Bg = (short*)((char*)d_ws + BG_OFF);
    float* L  = (float*)((char*)d_ws + L_OFF);

    k_prep<<<NB * NTTILE + 8, 256, 0, stream>>>(x, K, Ag, Bg);
    dim3 g1(NTTILE, 4, NB);                   // (32, 4, 32)
    k_gemm_scan<<<g1, 256, 0, stream>>>(Ag, Bg, L);
    k_fold<<<NB, 512, 0, stream>>>(L, out);
}